// Round 1
// baseline (563.504 us; speedup 1.0000x reference)
//
#include <hip/hip_runtime.h>
#include <stdint.h>

#define B_ 16
#define N_ 1025
#define D_ 512
#define H_ 8
#define HD 64
#define NP 1056           // padded N: 66*16 = 33*32
#define WM 34             // bitmask u32 words per row (covers 1088 bits)
#define M_ (B_*N_)        // 16400

typedef unsigned short u16;
typedef __attribute__((ext_vector_type(8))) short bf16x8;
typedef __attribute__((ext_vector_type(4))) short short4b;
typedef __attribute__((ext_vector_type(4))) u16 u16x4;
typedef __attribute__((ext_vector_type(4))) float f32x4;

__device__ __forceinline__ u16 f2bf(float f) {
  uint32_t u = __float_as_uint(f);
  u += 0x7FFFu + ((u >> 16) & 1u);   // RNE
  return (u16)(u >> 16);
}

// ---------------- K0: pack attn_mask into bitmask [NP][WM] u32 ----------------
__global__ void k_bitmask(const float* __restrict__ mask, uint32_t* __restrict__ bm) {
  int r = blockIdx.x;                       // 0..NP-1
  int wave = threadIdx.x >> 6, lane = threadIdx.x & 63;
  for (int chunk = wave; chunk < 17; chunk += 4) {   // 17 chunks of 64 bits = 1088 >= WM*32
    int kv = chunk * 64 + lane;
    bool pred = (r < N_) && (kv < N_) && (mask[(size_t)r * N_ + kv] != 0.0f);
    unsigned long long bal = __ballot(pred);
    if (lane == 0) {
      bm[r * WM + chunk * 2]     = (uint32_t)bal;
      if (chunk * 2 + 1 < WM) bm[r * WM + chunk * 2 + 1] = (uint32_t)(bal >> 32);
    }
  }
}

// ---------------- K1: convert+transpose weights to bf16 ----------------
__global__ void k_wconv(const float* __restrict__ wqkv, const float* __restrict__ wproj,
                        u16* __restrict__ wtq, u16* __restrict__ wtp) {
  int idx = blockIdx.x * 256 + threadIdx.x;
  if (idx < 3 * D_ * D_) {                 // w_qkv[k][c] -> wtq[c][k]
    int k = idx / (3 * D_), c = idx % (3 * D_);
    wtq[c * D_ + k] = f2bf(wqkv[idx]);
  }
  if (idx < D_ * D_) {                     // w_proj[k][c] -> wtp[c][k]
    int k = idx >> 9, c = idx & 511;
    wtp[c * D_ + k] = f2bf(wproj[idx]);
  }
}

// ---------------- K2: x -> bf16 ----------------
__global__ void k_xconv(const float* __restrict__ x, u16* __restrict__ xb) {
  int i = (blockIdx.x * 256 + threadIdx.x) * 4;
  float4 v = *reinterpret_cast<const float4*>(x + i);
  u16x4 o;
  o[0] = f2bf(v.x); o[1] = f2bf(v.y); o[2] = f2bf(v.z); o[3] = f2bf(v.w);
  *reinterpret_cast<u16x4*>(xb + i) = o;
}

// ---------------- K3: QKV GEMM -> Q (scaled), K, Vt ----------------
// grid (6, 1025), block 256 (4 waves). wave tile: 16m x 64n.
__global__ __launch_bounds__(256) void k_qkv(const u16* __restrict__ xb, const u16* __restrict__ wtq,
                                             u16* __restrict__ Q, u16* __restrict__ K,
                                             u16* __restrict__ Vt) {
  int m0 = blockIdx.y * 16;
  int wave = threadIdx.x >> 6, lane = threadIdx.x & 63;
  int n0 = blockIdx.x * 256 + wave * 64;
  int lq = lane & 15, lg = lane >> 4;
  f32x4 acc[4] = {{0,0,0,0},{0,0,0,0},{0,0,0,0},{0,0,0,0}};
  const u16* arow = xb + (size_t)(m0 + lq) * D_ + lg * 8;
  const u16* brow = wtq + (size_t)(n0 + lq) * D_ + lg * 8;
  for (int k0 = 0; k0 < D_; k0 += 32) {
    bf16x8 a = *reinterpret_cast<const bf16x8*>(arow + k0);
#pragma unroll
    for (int j = 0; j < 4; ++j) {
      bf16x8 b = *reinterpret_cast<const bf16x8*>(brow + j * 16 * D_ + k0);
      acc[j] = __builtin_amdgcn_mfma_f32_16x16x32_bf16(a, b, acc[j], 0, 0, 0);
    }
  }
#pragma unroll
  for (int j = 0; j < 4; ++j) {
    int c = n0 + j * 16 + lq;
    int which = c >> 9, h = (c >> 6) & 7, d = c & 63;
#pragma unroll
    for (int r = 0; r < 4; ++r) {
      int m = m0 + 4 * lg + r;
      int b = m / N_, n = m - b * N_;
      int bh = b * H_ + h;
      float v = acc[j][r];
      if (which == 0)      Q[((size_t)bh * NP + n) * HD + d] = f2bf(v * 0.125f);
      else if (which == 1) K[((size_t)bh * NP + n) * HD + d] = f2bf(v);
      else                 Vt[((size_t)bh * HD + d) * NP + n] = f2bf(v);
    }
  }
}

// ---------------- K4: flash attention with bitmask ----------------
// grid (66, 128): x = q-tile (16 rows), y = (b,h). block = 1 wave (64).
__global__ __launch_bounds__(64) void k_attn(const u16* __restrict__ Q, const u16* __restrict__ K,
                                             const u16* __restrict__ Vt, const uint32_t* __restrict__ bm,
                                             u16* __restrict__ O) {
  int qt = blockIdx.x, bh = blockIdx.y;
  int b = bh >> 3, h = bh & 7;
  int lane = threadIdx.x;
  int lq = lane & 15, lg = lane >> 4;
  int qbase = qt * 16;
  const u16* Qp = Q + ((size_t)bh * NP + qbase) * HD;
  const u16* Kp = K + (size_t)bh * NP * HD;
  const u16* Vp = Vt + (size_t)bh * HD * NP;
  const uint32_t* bmrow = bm + (size_t)(qbase + lq) * WM;

  bf16x8 qf0 = *reinterpret_cast<const bf16x8*>(Qp + lq * HD + lg * 8);
  bf16x8 qf1 = *reinterpret_cast<const bf16x8*>(Qp + lq * HD + 32 + lg * 8);

  f32x4 oacc[4] = {{0,0,0,0},{0,0,0,0},{0,0,0,0},{0,0,0,0}};
  float m_run = -INFINITY, l_run = 0.f;
  __shared__ u16 P[16][40];

  for (int kv0 = 0; kv0 < NP; kv0 += 32) {
    f32x4 s0 = {0,0,0,0}, s1 = {0,0,0,0};
    {
      const u16* kp = Kp + (size_t)(kv0 + lq) * HD + lg * 8;
      bf16x8 kf0 = *reinterpret_cast<const bf16x8*>(kp);
      bf16x8 kf1 = *reinterpret_cast<const bf16x8*>(kp + 32);
      s0 = __builtin_amdgcn_mfma_f32_16x16x32_bf16(kf0, qf0, s0, 0, 0, 0);
      s0 = __builtin_amdgcn_mfma_f32_16x16x32_bf16(kf1, qf1, s0, 0, 0, 0);
      const u16* kp2 = kp + 16 * HD;
      bf16x8 kf2 = *reinterpret_cast<const bf16x8*>(kp2);
      bf16x8 kf3 = *reinterpret_cast<const bf16x8*>(kp2 + 32);
      s1 = __builtin_amdgcn_mfma_f32_16x16x32_bf16(kf2, qf0, s1, 0, 0, 0);
      s1 = __builtin_amdgcn_mfma_f32_16x16x32_bf16(kf3, qf1, s1, 0, 0, 0);
    }
    // lane holds S[q = qbase+lq][kv0 + {4*lg+r, 16+4*lg+r}]
    uint32_t mw = bmrow[kv0 >> 5];
    float mt = -INFINITY;
    uint32_t bit0[4], bit1[4];
#pragma unroll
    for (int r = 0; r < 4; ++r) {
      bit0[r] = (mw >> (4 * lg + r)) & 1u;
      bit1[r] = (mw >> (16 + 4 * lg + r)) & 1u;
      if (bit0[r]) mt = fmaxf(mt, s0[r]);
      if (bit1[r]) mt = fmaxf(mt, s1[r]);
    }
    mt = fmaxf(mt, __shfl_xor(mt, 16));
    mt = fmaxf(mt, __shfl_xor(mt, 32));
    float mnew = fmaxf(m_run, mt);
    float p0[4], p1[4], ps = 0.f;
#pragma unroll
    for (int r = 0; r < 4; ++r) {
      p0[r] = bit0[r] ? __expf(s0[r] - mnew) : 0.f;
      p1[r] = bit1[r] ? __expf(s1[r] - mnew) : 0.f;
      ps += p0[r] + p1[r];
    }
    ps += __shfl_xor(ps, 16);
    ps += __shfl_xor(ps, 32);
    float fac = (mnew == m_run) ? 1.f : __expf(m_run - mnew);
    l_run = l_run * fac + ps;
    m_run = mnew;
    // write P (bf16) to LDS: row = q (lq), col = kv-local
    short4b pw0, pw1;
#pragma unroll
    for (int r = 0; r < 4; ++r) { pw0[r] = (short)f2bf(p0[r]); pw1[r] = (short)f2bf(p1[r]); }
    *reinterpret_cast<short4b*>(&P[lq][4 * lg]) = pw0;
    *reinterpret_cast<short4b*>(&P[lq][16 + 4 * lg]) = pw1;
    __syncthreads();
    // rescale O accumulators (row = q = 4*lg + r in D layout)
#pragma unroll
    for (int r = 0; r < 4; ++r) {
      float fr = __shfl(fac, 4 * lg + r);
#pragma unroll
      for (int j = 0; j < 4; ++j) oacc[j][r] *= fr;
    }
    // PV: A = P[16q x 32kv], B = Vt rows (contiguous kv)
    bf16x8 pf = *reinterpret_cast<bf16x8*>(&P[lq][lg * 8]);
#pragma unroll
    for (int j = 0; j < 4; ++j) {
      bf16x8 vf = *reinterpret_cast<const bf16x8*>(Vp + (size_t)(j * 16 + lq) * NP + kv0 + lg * 8);
      oacc[j] = __builtin_amdgcn_mfma_f32_16x16x32_bf16(pf, vf, oacc[j], 0, 0, 0);
    }
    __syncthreads();
  }
  // epilogue: divide by l, store to O[b*N+n][h*64 + d] as bf16
#pragma unroll
  for (int r = 0; r < 4; ++r) {
    int n = qbase + 4 * lg + r;
    float lr = __shfl(l_run, 4 * lg + r);
    float linv = (lr > 0.f) ? 1.f / lr : 0.f;
    if (n < N_) {
      size_t mrow = (size_t)b * N_ + n;
#pragma unroll
      for (int j = 0; j < 4; ++j)
        O[mrow * D_ + h * HD + j * 16 + lq] = f2bf(oacc[j][r] * linv);
    }
  }
}

// ---------------- K5: proj GEMM + bias -> fp32 ----------------
// grid (2, 1025), block 256
__global__ __launch_bounds__(256) void k_proj(const u16* __restrict__ ob, const u16* __restrict__ wtp,
                                              const float* __restrict__ bias, float* __restrict__ oproj) {
  int m0 = blockIdx.y * 16;
  int wave = threadIdx.x >> 6, lane = threadIdx.x & 63;
  int n0 = blockIdx.x * 256 + wave * 64;
  int lq = lane & 15, lg = lane >> 4;
  f32x4 acc[4] = {{0,0,0,0},{0,0,0,0},{0,0,0,0},{0,0,0,0}};
  const u16* arow = ob + (size_t)(m0 + lq) * D_ + lg * 8;
  const u16* brow = wtp + (size_t)(n0 + lq) * D_ + lg * 8;
  for (int k0 = 0; k0 < D_; k0 += 32) {
    bf16x8 a = *reinterpret_cast<const bf16x8*>(arow + k0);
#pragma unroll
    for (int j = 0; j < 4; ++j) {
      bf16x8 b = *reinterpret_cast<const bf16x8*>(brow + j * 16 * D_ + k0);
      acc[j] = __builtin_amdgcn_mfma_f32_16x16x32_bf16(a, b, acc[j], 0, 0, 0);
    }
  }
#pragma unroll
  for (int j = 0; j < 4; ++j) {
    int c = n0 + j * 16 + lq;
    float bv = bias[c];
#pragma unroll
    for (int r = 0; r < 4; ++r) {
      int m = m0 + 4 * lg + r;
      oproj[(size_t)m * D_ + c] = acc[j][r] + bv;
    }
  }
}

// ---------------- K6: LN + residual ----------------
__global__ __launch_bounds__(256) void k_ln(const float* __restrict__ op, const float* __restrict__ gamma,
                                            const float* __restrict__ beta, float* __restrict__ out) {
  int row = blockIdx.x;
  int t = threadIdx.x;
  const float* r = op + (size_t)row * D_;
  float v0 = r[t], v1 = r[t + 256];
  float s = v0 + v1, sq = v0 * v0 + v1 * v1;
#pragma unroll
  for (int off = 1; off < 64; off <<= 1) { s += __shfl_xor(s, off); sq += __shfl_xor(sq, off); }
  __shared__ float ls[4], lsq[4];
  int wave = t >> 6, lane = t & 63;
  if (lane == 0) { ls[wave] = s; lsq[wave] = sq; }
  __syncthreads();
  float S = ls[0] + ls[1] + ls[2] + ls[3];
  float SQ = lsq[0] + lsq[1] + lsq[2] + lsq[3];
  float mu = S * (1.f / 512.f);
  float var = SQ * (1.f / 512.f) - mu * mu;
  float rinv = rsqrtf(var + 1e-5f);
  float g0 = gamma[t], g1 = gamma[t + 256], b0 = beta[t], b1 = beta[t + 256];
  out[(size_t)row * D_ + t]       = v0 + (v0 - mu) * rinv * g0 + b0;
  out[(size_t)row * D_ + t + 256] = v1 + (v1 - mu) * rinv * g1 + b1;
}

extern "C" void kernel_launch(void* const* d_in, const int* in_sizes, int n_in,
                              void* d_out, int out_size, void* d_ws, size_t ws_size,
                              hipStream_t stream) {
  const float* x     = (const float*)d_in[0];
  const float* wqkv  = (const float*)d_in[1];
  const float* wproj = (const float*)d_in[2];
  const float* bproj = (const float*)d_in[3];
  const float* gamma = (const float*)d_in[4];
  const float* beta  = (const float*)d_in[5];
  const float* mask  = (const float*)d_in[6];
  float* out = (float*)d_out;

  char* ws = (char*)d_ws;
  size_t off = 0;
  auto alloc = [&](size_t bytes) {
    void* p = ws + off;
    off = (off + bytes + 255) & ~(size_t)255;
    return p;
  };
  uint32_t* bmask = (uint32_t*)alloc((size_t)NP * WM * 4);
  u16* wtq  = (u16*)alloc((size_t)3 * D_ * D_ * 2);
  u16* wtp  = (u16*)alloc((size_t)D_ * D_ * 2);
  u16* xb   = (u16*)alloc((size_t)M_ * D_ * 2);
  u16* Qb   = (u16*)alloc((size_t)128 * NP * HD * 2);
  u16* Kb   = (u16*)alloc((size_t)128 * NP * HD * 2);
  u16* Vtb  = (u16*)alloc((size_t)128 * HD * NP * 2);
  u16* Ob   = (u16*)alloc((size_t)M_ * D_ * 2);
  float* oproj = (float*)alloc((size_t)M_ * D_ * 4);

  k_bitmask<<<dim3(NP), dim3(256), 0, stream>>>(mask, bmask);
  k_wconv<<<dim3(3072), dim3(256), 0, stream>>>(wqkv, wproj, wtq, wtp);
  k_xconv<<<dim3(8200), dim3(256), 0, stream>>>(x, xb);
  k_qkv<<<dim3(6, 1025), dim3(256), 0, stream>>>(xb, wtq, Qb, Kb, Vtb);
  k_attn<<<dim3(66, 128), dim3(64), 0, stream>>>(Qb, Kb, Vtb, bmask, Ob);
  k_proj<<<dim3(2, 1025), dim3(256), 0, stream>>>(Ob, wtp, bproj, oproj);
  k_ln<<<dim3(M_), dim3(256), 0, stream>>>(oproj, gamma, beta, out);
}

// Round 2
// 345.007 us; speedup vs baseline: 1.6333x; 1.6333x over previous
//
#include <hip/hip_runtime.h>
#include <stdint.h>

#define B_ 16
#define N_ 1025
#define D_ 512
#define H_ 8
#define HD 64
#define NP 1056           // padded N: 66*16 = 33*32
#define WM 34             // bitmask u32 words per row (covers 1088 bits)
#define M_ (B_*N_)        // 16400 (real rows)
#define MP (B_*NP)        // 16896 = 132*128 padded rows

typedef unsigned short u16;
typedef __attribute__((ext_vector_type(8))) short bf16x8;
typedef __attribute__((ext_vector_type(4))) short short4b;
typedef __attribute__((ext_vector_type(8))) u16 u16x8;
typedef __attribute__((ext_vector_type(4))) float f32x4;

typedef __attribute__((address_space(1))) const uint32_t gld_t;
typedef __attribute__((address_space(3))) uint32_t lds_t;

__device__ __forceinline__ u16 f2bf(float f) {
  uint32_t u = __float_as_uint(f);
  u += 0x7FFFu + ((u >> 16) & 1u);   // RNE
  return (u16)(u >> 16);
}

__device__ __forceinline__ void gload16(const void* g, void* l) {
  __builtin_amdgcn_global_load_lds((gld_t*)g, (lds_t*)l, 16, 0, 0);
}

// ---------------- K0: pack attn_mask into bitmask [NP][WM] u32 ----------------
__global__ void k_bitmask(const float* __restrict__ mask, uint32_t* __restrict__ bm) {
  int r = blockIdx.x;                       // 0..NP-1
  int wave = threadIdx.x >> 6, lane = threadIdx.x & 63;
  for (int chunk = wave; chunk < 17; chunk += 4) {
    int kv = chunk * 64 + lane;
    bool pred = (r < N_) && (kv < N_) && (mask[(size_t)r * N_ + kv] != 0.0f);
    unsigned long long bal = __ballot(pred);
    if (lane == 0) {
      bm[r * WM + chunk * 2] = (uint32_t)bal;
      if (chunk * 2 + 1 < WM) bm[r * WM + chunk * 2 + 1] = (uint32_t)(bal >> 32);
    }
  }
}

// ---------------- K1: convert+transpose weights to bf16 ----------------
__global__ void k_wconv(const float* __restrict__ wqkv, const float* __restrict__ wproj,
                        u16* __restrict__ wtq, u16* __restrict__ wtp) {
  int idx = blockIdx.x * 256 + threadIdx.x;
  if (idx < 3 * D_ * D_) {                 // w_qkv[k][c] -> wtq[c][k]
    int k = idx / (3 * D_), c = idx % (3 * D_);
    wtq[c * D_ + k] = f2bf(wqkv[idx]);
  }
  if (idx < D_ * D_) {                     // w_proj[k][c] -> wtp[c][k]
    int k = idx >> 9, c = idx & 511;
    wtp[c * D_ + k] = f2bf(wproj[idx]);
  }
}

// ---------------- K2: x -> bf16, padded [B][NP][D], padded rows zeroed ----------------
__global__ void k_xconv(const float* __restrict__ x, u16* __restrict__ xb) {
  int i = blockIdx.x * 256 + threadIdx.x;  // 8-elem group index in padded space
  int idx = i * 8;
  int pr = idx >> 9;                        // padded row
  int col = idx & 511;
  int b = pr / NP, n = pr - b * NP;
  u16x8 o;
  if (n < N_) {
    const float* src = x + ((size_t)b * N_ + n) * D_ + col;
    float4 v0 = *reinterpret_cast<const float4*>(src);
    float4 v1 = *reinterpret_cast<const float4*>(src + 4);
    o[0] = f2bf(v0.x); o[1] = f2bf(v0.y); o[2] = f2bf(v0.z); o[3] = f2bf(v0.w);
    o[4] = f2bf(v1.x); o[5] = f2bf(v1.y); o[6] = f2bf(v1.z); o[7] = f2bf(v1.w);
  } else {
    o = (u16x8){0,0,0,0,0,0,0,0};
  }
  *reinterpret_cast<u16x8*>(xb + idx) = o;
}

// ================= 128x128 tiled GEMM (m97 structure) =================
// BK=64. LDS tiles [128 rows][64 bf16] = 128B/row; chunk = 16B unit.
// XOR swizzle: physical_chunk = logical_chunk ^ (row & 7)  (both-sides: pre-swizzled
// global source for the linear global_load_lds dest, swizzled ds_read address).

// ---------------- K3: QKV GEMM -> Q (scaled), K, Vt ----------------
// grid (12, 132), block 256 (4 waves, 2x2), wave tile 64x64 (4x4 frags)
__global__ __launch_bounds__(256) void k_qkv(const u16* __restrict__ xb, const u16* __restrict__ wtq,
                                             u16* __restrict__ Q, u16* __restrict__ K,
                                             u16* __restrict__ Vt) {
  __shared__ u16 sA[128 * 64];
  __shared__ u16 sB[128 * 64];
  const int m0 = blockIdx.y * 128;
  const int n0 = blockIdx.x * 128;
  const int t = threadIdx.x;
  const int wave = t >> 6, lane = t & 63;
  const int wm = wave >> 1, wn = wave & 1;
  const int lq = lane & 15, lg = lane >> 4;

  const int srow = lane >> 3;               // 0..7 (== staged row & 7)
  const int schunk = (lane & 7) ^ srow;     // logical chunk fetched (involution)

  f32x4 acc[4][4] = {};

  for (int k0 = 0; k0 < 512; k0 += 64) {
#pragma unroll
    for (int p = 0; p < 4; ++p) {
      int row = p * 32 + wave * 8 + srow;
      gload16(xb + (size_t)(m0 + row) * 512 + k0 + schunk * 8,
              sA + p * 2048 + wave * 512 + lane * 8);
      gload16(wtq + (size_t)(n0 + row) * 512 + k0 + schunk * 8,
              sB + p * 2048 + wave * 512 + lane * 8);
    }
    __syncthreads();
#pragma unroll
    for (int kk = 0; kk < 2; ++kk) {
      bf16x8 af[4], bff[4];
      const int pc = (kk * 4 + lg) ^ (lq & 7);   // physical chunk
#pragma unroll
      for (int f = 0; f < 4; ++f) {
        af[f]  = *reinterpret_cast<const bf16x8*>(sA + (wm * 64 + f * 16 + lq) * 64 + pc * 8);
        bff[f] = *reinterpret_cast<const bf16x8*>(sB + (wn * 64 + f * 16 + lq) * 64 + pc * 8);
      }
#pragma unroll
      for (int i = 0; i < 4; ++i)
#pragma unroll
        for (int j = 0; j < 4; ++j)
          acc[i][j] = __builtin_amdgcn_mfma_f32_16x16x32_bf16(af[i], bff[j], acc[i][j], 0, 0, 0);
    }
    __syncthreads();
  }
  // epilogue: c determines {Q,K,V}, head, dim; m -> (b, n) in padded space
#pragma unroll
  for (int j = 0; j < 4; ++j) {
    int c = n0 + wn * 64 + j * 16 + lq;
    int which = c >> 9, h = (c >> 6) & 7, d = c & 63;
#pragma unroll
    for (int i = 0; i < 4; ++i) {
      int mbase = m0 + wm * 64 + i * 16 + lg * 4;
#pragma unroll
      for (int r = 0; r < 4; ++r) {
        int m = mbase + r;
        int b = m / NP, n = m - b * NP;
        int bh = b * H_ + h;
        float v = acc[i][j][r];
        if (which == 0)      Q[((size_t)bh * NP + n) * HD + d] = f2bf(v * 0.125f);
        else if (which == 1) K[((size_t)bh * NP + n) * HD + d] = f2bf(v);
        else                 Vt[((size_t)bh * HD + d) * NP + n] = f2bf(v);
      }
    }
  }
}

// ---------------- K4: flash attention with bitmask ----------------
// grid (66, 128): x = q-tile (16 rows), y = (b,h). block = 1 wave (64).
__global__ __launch_bounds__(64) void k_attn(const u16* __restrict__ Q, const u16* __restrict__ K,
                                             const u16* __restrict__ Vt, const uint32_t* __restrict__ bm,
                                             u16* __restrict__ O) {
  int qt = blockIdx.x, bh = blockIdx.y;
  int b = bh >> 3, h = bh & 7;
  int lane = threadIdx.x;
  int lq = lane & 15, lg = lane >> 4;
  int qbase = qt * 16;
  const u16* Qp = Q + ((size_t)bh * NP + qbase) * HD;
  const u16* Kp = K + (size_t)bh * NP * HD;
  const u16* Vp = Vt + (size_t)bh * HD * NP;
  const uint32_t* bmrow = bm + (size_t)(qbase + lq) * WM;

  bf16x8 qf0 = *reinterpret_cast<const bf16x8*>(Qp + lq * HD + lg * 8);
  bf16x8 qf1 = *reinterpret_cast<const bf16x8*>(Qp + lq * HD + 32 + lg * 8);

  f32x4 oacc[4] = {{0,0,0,0},{0,0,0,0},{0,0,0,0},{0,0,0,0}};
  float m_run = -INFINITY, l_run = 0.f;
  __shared__ u16 P[16][40];

  for (int kv0 = 0; kv0 < NP; kv0 += 32) {
    f32x4 s0 = {0,0,0,0}, s1 = {0,0,0,0};
    {
      const u16* kp = Kp + (size_t)(kv0 + lq) * HD + lg * 8;
      bf16x8 kf0 = *reinterpret_cast<const bf16x8*>(kp);
      bf16x8 kf1 = *reinterpret_cast<const bf16x8*>(kp + 32);
      s0 = __builtin_amdgcn_mfma_f32_16x16x32_bf16(kf0, qf0, s0, 0, 0, 0);
      s0 = __builtin_amdgcn_mfma_f32_16x16x32_bf16(kf1, qf1, s0, 0, 0, 0);
      const u16* kp2 = kp + 16 * HD;
      bf16x8 kf2 = *reinterpret_cast<const bf16x8*>(kp2);
      bf16x8 kf3 = *reinterpret_cast<const bf16x8*>(kp2 + 32);
      s1 = __builtin_amdgcn_mfma_f32_16x16x32_bf16(kf2, qf0, s1, 0, 0, 0);
      s1 = __builtin_amdgcn_mfma_f32_16x16x32_bf16(kf3, qf1, s1, 0, 0, 0);
    }
    uint32_t mw = bmrow[kv0 >> 5];
    float mt = -INFINITY;
    uint32_t bit0[4], bit1[4];
#pragma unroll
    for (int r = 0; r < 4; ++r) {
      bit0[r] = (mw >> (4 * lg + r)) & 1u;
      bit1[r] = (mw >> (16 + 4 * lg + r)) & 1u;
      if (bit0[r]) mt = fmaxf(mt, s0[r]);
      if (bit1[r]) mt = fmaxf(mt, s1[r]);
    }
    mt = fmaxf(mt, __shfl_xor(mt, 16));
    mt = fmaxf(mt, __shfl_xor(mt, 32));
    float mnew = fmaxf(m_run, mt);
    float p0[4], p1[4], ps = 0.f;
#pragma unroll
    for (int r = 0; r < 4; ++r) {
      p0[r] = bit0[r] ? __expf(s0[r] - mnew) : 0.f;
      p1[r] = bit1[r] ? __expf(s1[r] - mnew) : 0.f;
      ps += p0[r] + p1[r];
    }
    ps += __shfl_xor(ps, 16);
    ps += __shfl_xor(ps, 32);
    float fac = (mnew == m_run) ? 1.f : __expf(m_run - mnew);
    l_run = l_run * fac + ps;
    m_run = mnew;
    short4b pw0, pw1;
#pragma unroll
    for (int r = 0; r < 4; ++r) { pw0[r] = (short)f2bf(p0[r]); pw1[r] = (short)f2bf(p1[r]); }
    *reinterpret_cast<short4b*>(&P[lq][4 * lg]) = pw0;
    *reinterpret_cast<short4b*>(&P[lq][16 + 4 * lg]) = pw1;
    __syncthreads();
#pragma unroll
    for (int r = 0; r < 4; ++r) {
      float fr = __shfl(fac, 4 * lg + r);
#pragma unroll
      for (int j = 0; j < 4; ++j) oacc[j][r] *= fr;
    }
    bf16x8 pf = *reinterpret_cast<bf16x8*>(&P[lq][lg * 8]);
#pragma unroll
    for (int j = 0; j < 4; ++j) {
      bf16x8 vf = *reinterpret_cast<const bf16x8*>(Vp + (size_t)(j * 16 + lq) * NP + kv0 + lg * 8);
      oacc[j] = __builtin_amdgcn_mfma_f32_16x16x32_bf16(pf, vf, oacc[j], 0, 0, 0);
    }
    __syncthreads();
  }
#pragma unroll
  for (int r = 0; r < 4; ++r) {
    int n = qbase + 4 * lg + r;
    float lr = __shfl(l_run, 4 * lg + r);
    float linv = (lr > 0.f) ? 1.f / lr : 0.f;
    size_t mrow = (size_t)b * NP + n;          // padded layout
#pragma unroll
    for (int j = 0; j < 4; ++j)
      O[mrow * D_ + h * HD + j * 16 + lq] = f2bf(oacc[j][r] * linv);
  }
}

// ---------------- K5: proj GEMM + bias -> fp32 (padded M) ----------------
// grid (4, 132), block 256, same structure as k_qkv
__global__ __launch_bounds__(256) void k_proj(const u16* __restrict__ ob, const u16* __restrict__ wtp,
                                              const float* __restrict__ bias, float* __restrict__ oproj) {
  __shared__ u16 sA[128 * 64];
  __shared__ u16 sB[128 * 64];
  const int m0 = blockIdx.y * 128;
  const int n0 = blockIdx.x * 128;
  const int t = threadIdx.x;
  const int wave = t >> 6, lane = t & 63;
  const int wm = wave >> 1, wn = wave & 1;
  const int lq = lane & 15, lg = lane >> 4;

  const int srow = lane >> 3;
  const int schunk = (lane & 7) ^ srow;

  f32x4 acc[4][4] = {};

  for (int k0 = 0; k0 < 512; k0 += 64) {
#pragma unroll
    for (int p = 0; p < 4; ++p) {
      int row = p * 32 + wave * 8 + srow;
      gload16(ob + (size_t)(m0 + row) * 512 + k0 + schunk * 8,
              sA + p * 2048 + wave * 512 + lane * 8);
      gload16(wtp + (size_t)(n0 + row) * 512 + k0 + schunk * 8,
              sB + p * 2048 + wave * 512 + lane * 8);
    }
    __syncthreads();
#pragma unroll
    for (int kk = 0; kk < 2; ++kk) {
      bf16x8 af[4], bff[4];
      const int pc = (kk * 4 + lg) ^ (lq & 7);
#pragma unroll
      for (int f = 0; f < 4; ++f) {
        af[f]  = *reinterpret_cast<const bf16x8*>(sA + (wm * 64 + f * 16 + lq) * 64 + pc * 8);
        bff[f] = *reinterpret_cast<const bf16x8*>(sB + (wn * 64 + f * 16 + lq) * 64 + pc * 8);
      }
#pragma unroll
      for (int i = 0; i < 4; ++i)
#pragma unroll
        for (int j = 0; j < 4; ++j)
          acc[i][j] = __builtin_amdgcn_mfma_f32_16x16x32_bf16(af[i], bff[j], acc[i][j], 0, 0, 0);
    }
    __syncthreads();
  }
#pragma unroll
  for (int j = 0; j < 4; ++j) {
    int c = n0 + wn * 64 + j * 16 + lq;
    float bv = bias[c];
#pragma unroll
    for (int i = 0; i < 4; ++i) {
      int mbase = m0 + wm * 64 + i * 16 + lg * 4;
#pragma unroll
      for (int r = 0; r < 4; ++r) {
        int m = mbase + r;
        oproj[(size_t)m * D_ + c] = acc[i][j][r] + bv;
      }
    }
  }
}

// ---------------- K6: LN + residual (reads padded, writes real) ----------------
__global__ __launch_bounds__(256) void k_ln(const float* __restrict__ op, const float* __restrict__ gamma,
                                            const float* __restrict__ beta, float* __restrict__ out) {
  int row = blockIdx.x;                      // 0..M_-1 (real rows)
  int b = row / N_, n = row - b * N_;
  int t = threadIdx.x;
  const float* r = op + ((size_t)b * NP + n) * D_;
  float v0 = r[t], v1 = r[t + 256];
  float s = v0 + v1, sq = v0 * v0 + v1 * v1;
#pragma unroll
  for (int off = 1; off < 64; off <<= 1) { s += __shfl_xor(s, off); sq += __shfl_xor(sq, off); }
  __shared__ float ls[4], lsq[4];
  int wave = t >> 6, lane = t & 63;
  if (lane == 0) { ls[wave] = s; lsq[wave] = sq; }
  __syncthreads();
  float S = ls[0] + ls[1] + ls[2] + ls[3];
  float SQ = lsq[0] + lsq[1] + lsq[2] + lsq[3];
  float mu = S * (1.f / 512.f);
  float var = SQ * (1.f / 512.f) - mu * mu;
  float rinv = rsqrtf(var + 1e-5f);
  float g0 = gamma[t], g1 = gamma[t + 256], b0 = beta[t], b1 = beta[t + 256];
  out[(size_t)row * D_ + t]       = v0 + (v0 - mu) * rinv * g0 + b0;
  out[(size_t)row * D_ + t + 256] = v1 + (v1 - mu) * rinv * g1 + b1;
}

extern "C" void kernel_launch(void* const* d_in, const int* in_sizes, int n_in,
                              void* d_out, int out_size, void* d_ws, size_t ws_size,
                              hipStream_t stream) {
  const float* x     = (const float*)d_in[0];
  const float* wqkv  = (const float*)d_in[1];
  const float* wproj = (const float*)d_in[2];
  const float* bproj = (const float*)d_in[3];
  const float* gamma = (const float*)d_in[4];
  const float* beta  = (const float*)d_in[5];
  const float* mask  = (const float*)d_in[6];
  float* out = (float*)d_out;

  char* ws = (char*)d_ws;
  size_t off = 0;
  auto alloc = [&](size_t bytes) {
    void* p = ws + off;
    off = (off + bytes + 255) & ~(size_t)255;
    return p;
  };
  uint32_t* bmask = (uint32_t*)alloc((size_t)NP * WM * 4);
  u16* wtq  = (u16*)alloc((size_t)3 * D_ * D_ * 2);
  u16* wtp  = (u16*)alloc((size_t)D_ * D_ * 2);
  u16* xb   = (u16*)alloc((size_t)MP * D_ * 2);
  u16* Qb   = (u16*)alloc((size_t)128 * NP * HD * 2);
  u16* Kb   = (u16*)alloc((size_t)128 * NP * HD * 2);
  u16* Vtb  = (u16*)alloc((size_t)128 * HD * NP * 2);
  u16* Ob   = (u16*)alloc((size_t)MP * D_ * 2);
  float* oproj = (float*)alloc((size_t)MP * D_ * 4);

  k_bitmask<<<dim3(NP), dim3(256), 0, stream>>>(mask, bmask);
  k_wconv<<<dim3(3072), dim3(256), 0, stream>>>(wqkv, wproj, wtq, wtp);
  k_xconv<<<dim3(MP * D_ / (256 * 8)), dim3(256), 0, stream>>>(x, xb);
  k_qkv<<<dim3(12, 132), dim3(256), 0, stream>>>(xb, wtq, Qb, Kb, Vtb);
  k_attn<<<dim3(66, 128), dim3(64), 0, stream>>>(Qb, Kb, Vtb, bmask, Ob);
  k_proj<<<dim3(4, 132), dim3(256), 0, stream>>>(Ob, wtp, bproj, oproj);
  k_ln<<<dim3(M_), dim3(256), 0, stream>>>(oproj, gamma, beta, out);
}

// Round 3
// 238.143 us; speedup vs baseline: 2.3662x; 1.4487x over previous
//
#include <hip/hip_runtime.h>
#include <stdint.h>

#define B_ 16
#define N_ 1025
#define D_ 512
#define H_ 8
#define HD 64
#define NP 1088           // padded N: 17*64
#define WM 34             // bitmask u32 words per row (34*32 = 1088 bits exactly)
#define M_ (B_*N_)        // 16400 (real rows)
#define MP (B_*NP)        // 17408 = 136*128 padded rows
#define NT 17             // KV tiles of 64

typedef unsigned short u16;
typedef __attribute__((ext_vector_type(8))) short bf16x8;
typedef __attribute__((ext_vector_type(4))) u16 u16x4;
typedef __attribute__((ext_vector_type(8))) u16 u16x8;
typedef __attribute__((ext_vector_type(4))) float f32x4;

typedef __attribute__((address_space(1))) const uint32_t gld_t;
typedef __attribute__((address_space(3))) uint32_t lds_t;

__device__ __forceinline__ u16 f2bf(float f) {
  uint32_t u = __float_as_uint(f);
  u += 0x7FFFu + ((u >> 16) & 1u);   // RNE
  return (u16)(u >> 16);
}

__device__ __forceinline__ void gload16(const void* g, void* l) {
  __builtin_amdgcn_global_load_lds((gld_t*)g, (lds_t*)l, 16, 0, 0);
}

// ---------------- K0: pack attn_mask into bitmask [NP][WM] u32 ----------------
__global__ void k_bitmask(const float* __restrict__ mask, uint32_t* __restrict__ bm) {
  int r = blockIdx.x;                       // 0..NP-1
  int wave = threadIdx.x >> 6, lane = threadIdx.x & 63;
  for (int chunk = wave; chunk < 17; chunk += 4) {   // 17*64 = 1088 bits
    int kv = chunk * 64 + lane;
    bool pred = (r < N_) && (kv < N_) && (mask[(size_t)r * N_ + kv] != 0.0f);
    unsigned long long bal = __ballot(pred);
    if (lane == 0) {
      bm[r * WM + chunk * 2]     = (uint32_t)bal;
      bm[r * WM + chunk * 2 + 1] = (uint32_t)(bal >> 32);
    }
  }
}

// ---------------- K1: convert+transpose weights to bf16 ----------------
__global__ void k_wconv(const float* __restrict__ wqkv, const float* __restrict__ wproj,
                        u16* __restrict__ wtq, u16* __restrict__ wtp) {
  int idx = blockIdx.x * 256 + threadIdx.x;
  if (idx < 3 * D_ * D_) {                 // w_qkv[k][c] -> wtq[c][k]
    int k = idx / (3 * D_), c = idx % (3 * D_);
    wtq[c * D_ + k] = f2bf(wqkv[idx]);
  }
  if (idx < D_ * D_) {                     // w_proj[k][c] -> wtp[c][k]
    int k = idx >> 9, c = idx & 511;
    wtp[c * D_ + k] = f2bf(wproj[idx]);
  }
}

// ---------------- K2: x -> bf16, padded [B][NP][D], padded rows zeroed ----------------
__global__ void k_xconv(const float* __restrict__ x, u16* __restrict__ xb) {
  int i = blockIdx.x * 256 + threadIdx.x;
  int idx = i * 8;
  int pr = idx >> 9;
  int col = idx & 511;
  int b = pr / NP, n = pr - b * NP;
  u16x8 o;
  if (n < N_) {
    const float* src = x + ((size_t)b * N_ + n) * D_ + col;
    float4 v0 = *reinterpret_cast<const float4*>(src);
    float4 v1 = *reinterpret_cast<const float4*>(src + 4);
    o[0] = f2bf(v0.x); o[1] = f2bf(v0.y); o[2] = f2bf(v0.z); o[3] = f2bf(v0.w);
    o[4] = f2bf(v1.x); o[5] = f2bf(v1.y); o[6] = f2bf(v1.z); o[7] = f2bf(v1.w);
  } else {
    o = (u16x8){0,0,0,0,0,0,0,0};
  }
  *reinterpret_cast<u16x8*>(xb + idx) = o;
}

// ================= 128x128 tiled GEMM (m97 structure) =================
// ---------------- K3: QKV GEMM -> Q (scaled), K, Vt ----------------
__global__ __launch_bounds__(256) void k_qkv(const u16* __restrict__ xb, const u16* __restrict__ wtq,
                                             u16* __restrict__ Q, u16* __restrict__ K,
                                             u16* __restrict__ Vt) {
  __shared__ u16 sA[128 * 64];
  __shared__ u16 sB[128 * 64];
  const int m0 = blockIdx.y * 128;
  const int n0 = blockIdx.x * 128;
  const int t = threadIdx.x;
  const int wave = t >> 6, lane = t & 63;
  const int wm = wave >> 1, wn = wave & 1;
  const int lq = lane & 15, lg = lane >> 4;

  const int srow = lane >> 3;
  const int schunk = (lane & 7) ^ srow;

  f32x4 acc[4][4] = {};

  for (int k0 = 0; k0 < 512; k0 += 64) {
#pragma unroll
    for (int p = 0; p < 4; ++p) {
      int row = p * 32 + wave * 8 + srow;
      gload16(xb + (size_t)(m0 + row) * 512 + k0 + schunk * 8,
              sA + p * 2048 + wave * 512 + lane * 8);
      gload16(wtq + (size_t)(n0 + row) * 512 + k0 + schunk * 8,
              sB + p * 2048 + wave * 512 + lane * 8);
    }
    __syncthreads();
#pragma unroll
    for (int kk = 0; kk < 2; ++kk) {
      bf16x8 af[4], bff[4];
      const int pc = (kk * 4 + lg) ^ (lq & 7);
#pragma unroll
      for (int f = 0; f < 4; ++f) {
        af[f]  = *reinterpret_cast<const bf16x8*>(sA + (wm * 64 + f * 16 + lq) * 64 + pc * 8);
        bff[f] = *reinterpret_cast<const bf16x8*>(sB + (wn * 64 + f * 16 + lq) * 64 + pc * 8);
      }
#pragma unroll
      for (int i = 0; i < 4; ++i)
#pragma unroll
        for (int j = 0; j < 4; ++j)
          acc[i][j] = __builtin_amdgcn_mfma_f32_16x16x32_bf16(af[i], bff[j], acc[i][j], 0, 0, 0);
    }
    __syncthreads();
  }
#pragma unroll
  for (int j = 0; j < 4; ++j) {
    int c = n0 + wn * 64 + j * 16 + lq;
    int which = c >> 9, h = (c >> 6) & 7, d = c & 63;
#pragma unroll
    for (int i = 0; i < 4; ++i) {
      int mbase = m0 + wm * 64 + i * 16 + lg * 4;
#pragma unroll
      for (int r = 0; r < 4; ++r) {
        int m = mbase + r;
        int b = m / NP, n = m - b * NP;
        int bh = b * H_ + h;
        float v = acc[i][j][r];
        if (which == 0)      Q[((size_t)bh * NP + n) * HD + d] = f2bf(v * 0.125f);
        else if (which == 1) K[((size_t)bh * NP + n) * HD + d] = f2bf(v);
        else                 Vt[((size_t)bh * HD + d) * NP + n] = f2bf(v);
      }
    }
  }
}

// ---------------- K4: flash attention, 4 waves, QBLK=64, KVBLK=64, staged+dbuf ----------------
// flat grid 17*128 = 2176, XCD-swizzled: each XCD gets 16 consecutive bh (K/V L2-resident)
__global__ __launch_bounds__(256) void k_attn(const u16* __restrict__ Q, const u16* __restrict__ K,
                                              const u16* __restrict__ Vt, const uint32_t* __restrict__ bm,
                                              u16* __restrict__ O) {
  __shared__ u16 sK[2][64 * 64];
  __shared__ u16 sV[2][64 * 64];
  __shared__ u16 sP[4][16 * 64];

  int bid = blockIdx.x;
  int wg = (bid & 7) * (NT * 128 / 8) + (bid >> 3);   // XCD swizzle (2176 % 8 == 0, bijective)
  int bh = wg / NT, qt = wg - bh * NT;
  int b = bh >> 3, h = bh & 7;
  int t = threadIdx.x;
  int w = t >> 6, lane = t & 63;
  int lq = lane & 15, lg = lane >> 4;
  int qbase = qt * 64;
  int qrow = qbase + w * 16 + lq;
  const u16* Qp = Q + ((size_t)bh * NP + qbase + w * 16) * HD;
  const u16* Kp = K + (size_t)bh * NP * HD;
  const u16* Vp = Vt + (size_t)bh * HD * NP;
  const uint32_t* bmrow = bm + (size_t)qrow * WM;

  bf16x8 qf0 = *reinterpret_cast<const bf16x8*>(Qp + lq * HD + lg * 8);
  bf16x8 qf1 = *reinterpret_cast<const bf16x8*>(Qp + lq * HD + 32 + lg * 8);

  // staging: 512 chunks of 16B per tile; thread t does chunks t and t+256
  const int c0 = t, c1 = t + 256;
  const int r0 = c0 >> 3, ch0 = (c0 & 7) ^ (r0 & 7);
  const int r1 = c1 >> 3, ch1 = (c1 & 7) ^ (r1 & 7);

  f32x4 oacc[4] = {};
  float m_run = -INFINITY, l_run = 0.f;

#define STAGE(buf, kv0_)                                                        \
  {                                                                             \
    gload16(Kp + (size_t)((kv0_) + r0) * HD + ch0 * 8, &sK[buf][c0 * 8]);       \
    gload16(Kp + (size_t)((kv0_) + r1) * HD + ch1 * 8, &sK[buf][c1 * 8]);       \
    gload16(Vp + (size_t)r0 * NP + (kv0_) + ch0 * 8,   &sV[buf][c0 * 8]);       \
    gload16(Vp + (size_t)r1 * NP + (kv0_) + ch1 * 8,   &sV[buf][c1 * 8]);       \
  }

  STAGE(0, 0);
  __syncthreads();
  int cur = 0;
  for (int ti = 0; ti < NT; ++ti) {
    int kv0 = ti * 64;
    if (ti + 1 < NT) STAGE(cur ^ 1, kv0 + 64);

    // QK^T: s[f][r] = S[q=lq][kv = kv0 + f*16 + 4*lg + r]
    f32x4 s[4] = {};
#pragma unroll
    for (int kk = 0; kk < 2; ++kk) {
      bf16x8 qf = kk ? qf1 : qf0;
      int pc = (kk * 4 + lg) ^ (lq & 7);
#pragma unroll
      for (int f = 0; f < 4; ++f) {
        bf16x8 kf = *reinterpret_cast<const bf16x8*>(&sK[cur][(f * 16 + lq) * 64 + pc * 8]);
        s[f] = __builtin_amdgcn_mfma_f32_16x16x32_bf16(kf, qf, s[f], 0, 0, 0);
      }
    }

    uint32_t w0 = bmrow[ti * 2], w1 = bmrow[ti * 2 + 1];
    float mt = -INFINITY;
#pragma unroll
    for (int f = 0; f < 4; ++f) {
      uint32_t mw = (f & 2) ? w1 : w0;
#pragma unroll
      for (int r = 0; r < 4; ++r) {
        if ((mw >> ((f & 1) * 16 + 4 * lg + r)) & 1u) mt = fmaxf(mt, s[f][r]);
      }
    }
    mt = fmaxf(mt, __shfl_xor(mt, 16));
    mt = fmaxf(mt, __shfl_xor(mt, 32));
    float mnew = fmaxf(m_run, mt);
    float ps = 0.f;
#pragma unroll
    for (int f = 0; f < 4; ++f) {
      uint32_t mw = (f & 2) ? w1 : w0;
#pragma unroll
      for (int r = 0; r < 4; ++r) {
        float pv = ((mw >> ((f & 1) * 16 + 4 * lg + r)) & 1u) ? __expf(s[f][r] - mnew) : 0.f;
        s[f][r] = pv;
        ps += pv;
      }
    }
    ps += __shfl_xor(ps, 16);
    ps += __shfl_xor(ps, 32);
    float fac = (mnew == m_run) ? 1.f : __expf(m_run - mnew);
    l_run = l_run * fac + ps;
    m_run = mnew;

    // P -> LDS (bf16), XOR-swizzled chunks; row = lq, cols f*16+4lg..+3
#pragma unroll
    for (int f = 0; f < 4; ++f) {
      u16x4 pw;
#pragma unroll
      for (int r = 0; r < 4; ++r) pw[r] = f2bf(s[f][r]);
      int pch = (2 * f + (lg >> 1)) ^ (lq & 7);
      *reinterpret_cast<u16x4*>(&sP[w][lq * 64 + pch * 8 + (lg & 1) * 4]) = pw;
    }

    // rescale O accumulators (row q-local = 4*lg + r)
#pragma unroll
    for (int r = 0; r < 4; ++r) {
      float fr = __shfl(fac, 4 * lg + r);
#pragma unroll
      for (int j = 0; j < 4; ++j) oacc[j][r] *= fr;
    }

    // PV: A = P[16q x 64kv] (own wave's LDS), B = sV rows (d), k = kv
#pragma unroll
    for (int kk = 0; kk < 2; ++kk) {
      int pc = (kk * 4 + lg) ^ (lq & 7);
      bf16x8 pf = *reinterpret_cast<const bf16x8*>(&sP[w][lq * 64 + pc * 8]);
#pragma unroll
      for (int j = 0; j < 4; ++j) {
        bf16x8 vf = *reinterpret_cast<const bf16x8*>(&sV[cur][(j * 16 + lq) * 64 + pc * 8]);
        oacc[j] = __builtin_amdgcn_mfma_f32_16x16x32_bf16(pf, vf, oacc[j], 0, 0, 0);
      }
    }
    __syncthreads();
    cur ^= 1;
  }
#undef STAGE

#pragma unroll
  for (int r = 0; r < 4; ++r) {
    int n = qbase + w * 16 + 4 * lg + r;
    float lr = __shfl(l_run, 4 * lg + r);
    float linv = (lr > 0.f) ? 1.f / lr : 0.f;
    size_t mrow = (size_t)b * NP + n;
#pragma unroll
    for (int j = 0; j < 4; ++j)
      O[mrow * D_ + h * HD + j * 16 + lq] = f2bf(oacc[j][r] * linv);
  }
}

// ---------------- K5: proj GEMM + bias -> fp32 (padded M) ----------------
__global__ __launch_bounds__(256) void k_proj(const u16* __restrict__ ob, const u16* __restrict__ wtp,
                                              const float* __restrict__ bias, float* __restrict__ oproj) {
  __shared__ u16 sA[128 * 64];
  __shared__ u16 sB[128 * 64];
  const int m0 = blockIdx.y * 128;
  const int n0 = blockIdx.x * 128;
  const int t = threadIdx.x;
  const int wave = t >> 6, lane = t & 63;
  const int wm = wave >> 1, wn = wave & 1;
  const int lq = lane & 15, lg = lane >> 4;

  const int srow = lane >> 3;
  const int schunk = (lane & 7) ^ srow;

  f32x4 acc[4][4] = {};

  for (int k0 = 0; k0 < 512; k0 += 64) {
#pragma unroll
    for (int p = 0; p < 4; ++p) {
      int row = p * 32 + wave * 8 + srow;
      gload16(ob + (size_t)(m0 + row) * 512 + k0 + schunk * 8,
              sA + p * 2048 + wave * 512 + lane * 8);
      gload16(wtp + (size_t)(n0 + row) * 512 + k0 + schunk * 8,
              sB + p * 2048 + wave * 512 + lane * 8);
    }
    __syncthreads();
#pragma unroll
    for (int kk = 0; kk < 2; ++kk) {
      bf16x8 af[4], bff[4];
      const int pc = (kk * 4 + lg) ^ (lq & 7);
#pragma unroll
      for (int f = 0; f < 4; ++f) {
        af[f]  = *reinterpret_cast<const bf16x8*>(sA + (wm * 64 + f * 16 + lq) * 64 + pc * 8);
        bff[f] = *reinterpret_cast<const bf16x8*>(sB + (wn * 64 + f * 16 + lq) * 64 + pc * 8);
      }
#pragma unroll
      for (int i = 0; i < 4; ++i)
#pragma unroll
        for (int j = 0; j < 4; ++j)
          acc[i][j] = __builtin_amdgcn_mfma_f32_16x16x32_bf16(af[i], bff[j], acc[i][j], 0, 0, 0);
    }
    __syncthreads();
  }
#pragma unroll
  for (int j = 0; j < 4; ++j) {
    int c = n0 + wn * 64 + j * 16 + lq;
    float bv = bias[c];
#pragma unroll
    for (int i = 0; i < 4; ++i) {
      int mbase = m0 + wm * 64 + i * 16 + lg * 4;
#pragma unroll
      for (int r = 0; r < 4; ++r) {
        int m = mbase + r;
        oproj[(size_t)m * D_ + c] = acc[i][j][r] + bv;
      }
    }
  }
}

// ---------------- K6: LN + residual (reads padded, writes real) ----------------
__global__ __launch_bounds__(256) void k_ln(const float* __restrict__ op, const float* __restrict__ gamma,
                                            const float* __restrict__ beta, float* __restrict__ out) {
  int row = blockIdx.x;
  int b = row / N_, n = row - b * N_;
  int t = threadIdx.x;
  const float* r = op + ((size_t)b * NP + n) * D_;
  float v0 = r[t], v1 = r[t + 256];
  float s = v0 + v1, sq = v0 * v0 + v1 * v1;
#pragma unroll
  for (int off = 1; off < 64; off <<= 1) { s += __shfl_xor(s, off); sq += __shfl_xor(sq, off); }
  __shared__ float ls[4], lsq[4];
  int wave = t >> 6, lane = t & 63;
  if (lane == 0) { ls[wave] = s; lsq[wave] = sq; }
  __syncthreads();
  float S = ls[0] + ls[1] + ls[2] + ls[3];
  float SQ = lsq[0] + lsq[1] + lsq[2] + lsq[3];
  float mu = S * (1.f / 512.f);
  float var = SQ * (1.f / 512.f) - mu * mu;
  float rinv = rsqrtf(var + 1e-5f);
  float g0 = gamma[t], g1 = gamma[t + 256], b0 = beta[t], b1 = beta[t + 256];
  out[(size_t)row * D_ + t]       = v0 + (v0 - mu) * rinv * g0 + b0;
  out[(size_t)row * D_ + t + 256] = v1 + (v1 - mu) * rinv * g1 + b1;
}

extern "C" void kernel_launch(void* const* d_in, const int* in_sizes, int n_in,
                              void* d_out, int out_size, void* d_ws, size_t ws_size,
                              hipStream_t stream) {
  const float* x     = (const float*)d_in[0];
  const float* wqkv  = (const float*)d_in[1];
  const float* wproj = (const float*)d_in[2];
  const float* bproj = (const float*)d_in[3];
  const float* gamma = (const float*)d_in[4];
  const float* beta  = (const float*)d_in[5];
  const float* mask  = (const float*)d_in[6];
  float* out = (float*)d_out;

  char* ws = (char*)d_ws;
  size_t off = 0;
  auto alloc = [&](size_t bytes) {
    void* p = ws + off;
    off = (off + bytes + 255) & ~(size_t)255;
    return p;
  };
  uint32_t* bmask = (uint32_t*)alloc((size_t)NP * WM * 4);
  u16* wtq  = (u16*)alloc((size_t)3 * D_ * D_ * 2);
  u16* wtp  = (u16*)alloc((size_t)D_ * D_ * 2);
  u16* xb   = (u16*)alloc((size_t)MP * D_ * 2);
  u16* Qb   = (u16*)alloc((size_t)128 * NP * HD * 2);
  u16* Kb   = (u16*)alloc((size_t)128 * NP * HD * 2);
  u16* Vtb  = (u16*)alloc((size_t)128 * HD * NP * 2);
  u16* Ob   = (u16*)alloc((size_t)MP * D_ * 2);
  float* oproj = (float*)alloc((size_t)MP * D_ * 4);

  k_bitmask<<<dim3(NP), dim3(256), 0, stream>>>(mask, bmask);
  k_wconv<<<dim3(3072), dim3(256), 0, stream>>>(wqkv, wproj, wtq, wtp);
  k_xconv<<<dim3(MP * D_ / (256 * 8)), dim3(256), 0, stream>>>(x, xb);
  k_qkv<<<dim3(12, MP / 128), dim3(256), 0, stream>>>(xb, wtq, Qb, Kb, Vtb);
  k_attn<<<dim3(NT * 128), dim3(256), 0, stream>>>(Qb, Kb, Vtb, bmask, Ob);
  k_proj<<<dim3(4, MP / 128), dim3(256), 0, stream>>>(Ob, wtp, bproj, oproj);
  k_ln<<<dim3(M_), dim3(256), 0, stream>>>(oproj, gamma, beta, out);
}

// Round 4
// 209.716 us; speedup vs baseline: 2.6870x; 1.1355x over previous
//
#include <hip/hip_runtime.h>
#include <stdint.h>

#define B_ 16
#define N_ 1025
#define D_ 512
#define H_ 8
#define HD 64
#define NP 1088           // padded N: 17*64
#define WM 34             // bitmask u32 words per row (34*32 = 1088 bits exactly)
#define M_ (B_*N_)        // 16400 (real rows)
#define MP (B_*NP)        // 17408 = 136*128 padded rows
#define NT 17             // KV tiles of 64

typedef unsigned short u16;
typedef __attribute__((ext_vector_type(8))) short bf16x8;
typedef __attribute__((ext_vector_type(8))) u16 u16x8;
typedef __attribute__((ext_vector_type(4))) float f32x4;

typedef __attribute__((address_space(1))) const uint32_t gld_t;
typedef __attribute__((address_space(3))) uint32_t lds_t;

__device__ __forceinline__ u16 f2bf(float f) {
  uint32_t u = __float_as_uint(f);
  u += 0x7FFFu + ((u >> 16) & 1u);   // RNE
  return (u16)(u >> 16);
}

__device__ __forceinline__ uint32_t cvtpk(float a, float b) {
  uint32_t r;
  asm("v_cvt_pk_bf16_f32 %0, %1, %2" : "=v"(r) : "v"(a), "v"(b));
  return r;
}

__device__ __forceinline__ void gload16(const void* g, void* l) {
  __builtin_amdgcn_global_load_lds((gld_t*)g, (lds_t*)l, 16, 0, 0);
}

// ---------------- K0: pack attn_mask into bitmask [NP][WM] u32 ----------------
__global__ void k_bitmask(const float* __restrict__ mask, uint32_t* __restrict__ bm) {
  int r = blockIdx.x;
  int wave = threadIdx.x >> 6, lane = threadIdx.x & 63;
  for (int chunk = wave; chunk < 17; chunk += 4) {
    int kv = chunk * 64 + lane;
    bool pred = (r < N_) && (kv < N_) && (mask[(size_t)r * N_ + kv] != 0.0f);
    unsigned long long bal = __ballot(pred);
    if (lane == 0) {
      bm[r * WM + chunk * 2]     = (uint32_t)bal;
      bm[r * WM + chunk * 2 + 1] = (uint32_t)(bal >> 32);
    }
  }
}

// ---------------- K1: convert+transpose weights to bf16 ----------------
__global__ void k_wconv(const float* __restrict__ wqkv, const float* __restrict__ wproj,
                        u16* __restrict__ wtq, u16* __restrict__ wtp) {
  int idx = blockIdx.x * 256 + threadIdx.x;
  if (idx < 3 * D_ * D_) {
    int k = idx / (3 * D_), c = idx % (3 * D_);
    wtq[c * D_ + k] = f2bf(wqkv[idx]);
  }
  if (idx < D_ * D_) {
    int k = idx >> 9, c = idx & 511;
    wtp[c * D_ + k] = f2bf(wproj[idx]);
  }
}

// ---------------- K2: x -> bf16, padded [B][NP][D], padded rows zeroed ----------------
__global__ void k_xconv(const float* __restrict__ x, u16* __restrict__ xb) {
  int i = blockIdx.x * 256 + threadIdx.x;
  int idx = i * 8;
  int pr = idx >> 9;
  int col = idx & 511;
  int b = pr / NP, n = pr - b * NP;
  u16x8 o;
  if (n < N_) {
    const float* src = x + ((size_t)b * N_ + n) * D_ + col;
    float4 v0 = *reinterpret_cast<const float4*>(src);
    float4 v1 = *reinterpret_cast<const float4*>(src + 4);
    o[0] = f2bf(v0.x); o[1] = f2bf(v0.y); o[2] = f2bf(v0.z); o[3] = f2bf(v0.w);
    o[4] = f2bf(v1.x); o[5] = f2bf(v1.y); o[6] = f2bf(v1.z); o[7] = f2bf(v1.w);
  } else {
    o = (u16x8){0,0,0,0,0,0,0,0};
  }
  *reinterpret_cast<u16x8*>(xb + idx) = o;
}

// ================= 128x128 tiled GEMM, 2-phase dbuf (T3 minimum) =================

// ---------------- K3: QKV GEMM -> Q (scaled by 0.125*log2e), K, V ----------------
__global__ __launch_bounds__(256) void k_qkv(const u16* __restrict__ xb, const u16* __restrict__ wtq,
                                             u16* __restrict__ Q, u16* __restrict__ K,
                                             u16* __restrict__ V) {
  __shared__ u16 sA[2][128 * 64];
  __shared__ u16 sB[2][128 * 64];
  const int m0 = blockIdx.y * 128;
  const int n0 = blockIdx.x * 128;
  const int t = threadIdx.x;
  const int wave = t >> 6, lane = t & 63;
  const int wm = wave >> 1, wn = wave & 1;
  const int lq = lane & 15, lg = lane >> 4;

  const int srow = lane >> 3;
  const int schunk = (lane & 7) ^ srow;

  f32x4 acc[4][4] = {};

#define QSTAGE(buf, k0_)                                                          \
  {                                                                               \
    _Pragma("unroll")                                                             \
    for (int p = 0; p < 4; ++p) {                                                 \
      int row = p * 32 + wave * 8 + srow;                                         \
      gload16(xb + (size_t)(m0 + row) * 512 + (k0_) + schunk * 8,                 \
              &sA[buf][p * 2048 + wave * 512 + lane * 8]);                        \
      gload16(wtq + (size_t)(n0 + row) * 512 + (k0_) + schunk * 8,                \
              &sB[buf][p * 2048 + wave * 512 + lane * 8]);                        \
    }                                                                             \
  }

  QSTAGE(0, 0);
  __syncthreads();
  int cur = 0;
  for (int k0 = 0; k0 < 512; k0 += 64) {
    if (k0 < 448) QSTAGE(cur ^ 1, k0 + 64);
#pragma unroll
    for (int kk = 0; kk < 2; ++kk) {
      bf16x8 af[4], bff[4];
      const int pc = (kk * 4 + lg) ^ (lq & 7);
#pragma unroll
      for (int f = 0; f < 4; ++f) {
        af[f]  = *reinterpret_cast<const bf16x8*>(&sA[cur][(wm * 64 + f * 16 + lq) * 64 + pc * 8]);
        bff[f] = *reinterpret_cast<const bf16x8*>(&sB[cur][(wn * 64 + f * 16 + lq) * 64 + pc * 8]);
      }
#pragma unroll
      for (int i = 0; i < 4; ++i)
#pragma unroll
        for (int j = 0; j < 4; ++j)
          acc[i][j] = __builtin_amdgcn_mfma_f32_16x16x32_bf16(af[i], bff[j], acc[i][j], 0, 0, 0);
    }
    __syncthreads();
    cur ^= 1;
  }
#undef QSTAGE

#pragma unroll
  for (int j = 0; j < 4; ++j) {
    int c = n0 + wn * 64 + j * 16 + lq;
    int which = c >> 9, h = (c >> 6) & 7, d = c & 63;
#pragma unroll
    for (int i = 0; i < 4; ++i) {
      int mbase = m0 + wm * 64 + i * 16 + lg * 4;
#pragma unroll
      for (int r = 0; r < 4; ++r) {
        int m = mbase + r;
        int b = m / NP, n = m - b * NP;
        int bh = b * H_ + h;
        float v = acc[i][j][r];
        if (which == 0)      Q[((size_t)bh * NP + n) * HD + d] = f2bf(v * 0.18033688f); // 0.125*log2(e)
        else if (which == 1) K[((size_t)bh * NP + n) * HD + d] = f2bf(v);
        else                 V[((size_t)bh * NP + n) * HD + d] = f2bf(v);  // coalesced [n][d]
      }
    }
  }
}

// ---------------- K3b: transpose V [bh][n][d] -> Vt [bh][d][n] ----------------
__global__ __launch_bounds__(256) void k_vt(const u16* __restrict__ V, u16* __restrict__ Vt) {
  __shared__ u16 s[64][72];
  int n0 = blockIdx.x * 64, bh = blockIdx.y;
  int t = threadIdx.x;
  int r = t >> 3, c = t & 7;
  const u16* src = V + ((size_t)bh * NP + n0) * HD;
  *reinterpret_cast<u16x8*>(&s[r][c * 8])      = *reinterpret_cast<const u16x8*>(src + r * HD + c * 8);
  *reinterpret_cast<u16x8*>(&s[r + 32][c * 8]) = *reinterpret_cast<const u16x8*>(src + (r + 32) * HD + c * 8);
  __syncthreads();
  int d = t >> 2, cc0 = t & 3;
  u16* dst = Vt + ((size_t)bh * HD + d) * NP + n0;
#pragma unroll
  for (int rep = 0; rep < 2; ++rep) {
    int cc = cc0 + rep * 4;
    u16x8 o;
#pragma unroll
    for (int jj = 0; jj < 8; ++jj) o[jj] = s[cc * 8 + jj][d];
    *reinterpret_cast<u16x8*>(dst + cc * 8) = o;
  }
}

// ---------------- K4: flash attention, fixed-max softmax (p = 2^s) ----------------
__global__ __launch_bounds__(256) void k_attn(const u16* __restrict__ Q, const u16* __restrict__ K,
                                              const u16* __restrict__ Vt, const uint32_t* __restrict__ bm,
                                              u16* __restrict__ O) {
  __shared__ u16 sK[2][64 * 64];
  __shared__ u16 sV[2][64 * 64];
  __shared__ u16 sP[4][16 * 64];

  int bid = blockIdx.x;
  int wg = (bid & 7) * (NT * 128 / 8) + (bid >> 3);   // XCD swizzle (2176 % 8 == 0)
  int bh = wg / NT, qt = wg - bh * NT;
  int b = bh >> 3, h = bh & 7;
  int t = threadIdx.x;
  int w = t >> 6, lane = t & 63;
  int lq = lane & 15, lg = lane >> 4;
  int qbase = qt * 64;
  int qrow = qbase + w * 16 + lq;
  const u16* Qp = Q + ((size_t)bh * NP + qbase + w * 16) * HD;
  const u16* Kp = K + (size_t)bh * NP * HD;
  const u16* Vp = Vt + (size_t)bh * HD * NP;
  const uint32_t* bmrow = bm + (size_t)qrow * WM;

  bf16x8 qf0 = *reinterpret_cast<const bf16x8*>(Qp + lq * HD + lg * 8);
  bf16x8 qf1 = *reinterpret_cast<const bf16x8*>(Qp + lq * HD + 32 + lg * 8);

  const int c0 = t, c1 = t + 256;
  const int r0 = c0 >> 3, ch0 = (c0 & 7) ^ (r0 & 7);
  const int r1 = c1 >> 3, ch1 = (c1 & 7) ^ (r1 & 7);

  f32x4 oacc[4] = {};
  float lpart = 0.f;

#define STAGE(buf, kv0_)                                                        \
  {                                                                             \
    gload16(Kp + (size_t)((kv0_) + r0) * HD + ch0 * 8, &sK[buf][c0 * 8]);       \
    gload16(Kp + (size_t)((kv0_) + r1) * HD + ch1 * 8, &sK[buf][c1 * 8]);       \
    gload16(Vp + (size_t)r0 * NP + (kv0_) + ch0 * 8,   &sV[buf][c0 * 8]);       \
    gload16(Vp + (size_t)r1 * NP + (kv0_) + ch1 * 8,   &sV[buf][c1 * 8]);       \
  }

  STAGE(0, 0);
  __syncthreads();
  int cur = 0;
  for (int ti = 0; ti < NT; ++ti) {
    int kv0 = ti * 64;
    if (ti + 1 < NT) STAGE(cur ^ 1, kv0 + 64);

    // QK^T: s[f][r] = S[q=lq][kv = kv0 + f*16 + 4*lg + r] (already in log2 domain)
    f32x4 s[4] = {};
#pragma unroll
    for (int kk = 0; kk < 2; ++kk) {
      bf16x8 qf = kk ? qf1 : qf0;
      int pc = (kk * 4 + lg) ^ (lq & 7);
#pragma unroll
      for (int f = 0; f < 4; ++f) {
        bf16x8 kf = *reinterpret_cast<const bf16x8*>(&sK[cur][(f * 16 + lq) * 64 + pc * 8]);
        s[f] = __builtin_amdgcn_mfma_f32_16x16x32_bf16(kf, qf, s[f], 0, 0, 0);
      }
    }

    // mask + exp2 (no running max; |s| small by construction)
    uint32_t w0 = bmrow[ti * 2], w1 = bmrow[ti * 2 + 1];
    uint32_t u0 = w0 >> (4 * lg);
    uint32_t u1 = w1 >> (4 * lg);
#pragma unroll
    for (int f = 0; f < 4; ++f) {
      uint32_t uu = (f & 2) ? u1 : u0;
      int sh = (f & 1) * 16;
#pragma unroll
      for (int r = 0; r < 4; ++r) {
        float pv = (uu & (1u << (sh + r))) ? exp2f(s[f][r]) : 0.f;
        s[f][r] = pv;
        lpart += pv;
      }
    }

    // P -> LDS (bf16 via cvt_pk), XOR-swizzled chunks
#pragma unroll
    for (int f = 0; f < 4; ++f) {
      uint2 pw;
      pw.x = cvtpk(s[f][0], s[f][1]);
      pw.y = cvtpk(s[f][2], s[f][3]);
      int pch = (2 * f + (lg >> 1)) ^ (lq & 7);
      *reinterpret_cast<uint2*>(&sP[w][lq * 64 + pch * 8 + (lg & 1) * 4]) = pw;
    }

    // PV
#pragma unroll
    for (int kk = 0; kk < 2; ++kk) {
      int pc = (kk * 4 + lg) ^ (lq & 7);
      bf16x8 pf = *reinterpret_cast<const bf16x8*>(&sP[w][lq * 64 + pc * 8]);
#pragma unroll
      for (int j = 0; j < 4; ++j) {
        bf16x8 vf = *reinterpret_cast<const bf16x8*>(&sV[cur][(j * 16 + lq) * 64 + pc * 8]);
        oacc[j] = __builtin_amdgcn_mfma_f32_16x16x32_bf16(pf, vf, oacc[j], 0, 0, 0);
      }
    }
    __syncthreads();
    cur ^= 1;
  }
#undef STAGE

  // deferred l reduction: every lane gets row-lq total
  lpart += __shfl_xor(lpart, 16);
  lpart += __shfl_xor(lpart, 32);

#pragma unroll
  for (int r = 0; r < 4; ++r) {
    int n = qbase + w * 16 + 4 * lg + r;
    float lr = __shfl(lpart, 4 * lg + r);
    float linv = (lr > 0.f) ? 1.f / lr : 0.f;
    size_t mrow = (size_t)b * NP + n;
#pragma unroll
    for (int j = 0; j < 4; ++j)
      O[mrow * D_ + h * HD + j * 16 + lq] = f2bf(oacc[j][r] * linv);
  }
}

// ---------------- K5: proj GEMM + bias -> fp32 (padded M), 2-phase dbuf ----------------
__global__ __launch_bounds__(256) void k_proj(const u16* __restrict__ ob, const u16* __restrict__ wtp,
                                              const float* __restrict__ bias, float* __restrict__ oproj) {
  __shared__ u16 sA[2][128 * 64];
  __shared__ u16 sB[2][128 * 64];
  const int m0 = blockIdx.y * 128;
  const int n0 = blockIdx.x * 128;
  const int t = threadIdx.x;
  const int wave = t >> 6, lane = t & 63;
  const int wm = wave >> 1, wn = wave & 1;
  const int lq = lane & 15, lg = lane >> 4;

  const int srow = lane >> 3;
  const int schunk = (lane & 7) ^ srow;

  f32x4 acc[4][4] = {};

#define PSTAGE(buf, k0_)                                                          \
  {                                                                               \
    _Pragma("unroll")                                                             \
    for (int p = 0; p < 4; ++p) {                                                 \
      int row = p * 32 + wave * 8 + srow;                                         \
      gload16(ob + (size_t)(m0 + row) * 512 + (k0_) + schunk * 8,                 \
              &sA[buf][p * 2048 + wave * 512 + lane * 8]);                        \
      gload16(wtp + (size_t)(n0 + row) * 512 + (k0_) + schunk * 8,                \
              &sB[buf][p * 2048 + wave * 512 + lane * 8]);                        \
    }                                                                             \
  }

  PSTAGE(0, 0);
  __syncthreads();
  int cur = 0;
  for (int k0 = 0; k0 < 512; k0 += 64) {
    if (k0 < 448) PSTAGE(cur ^ 1, k0 + 64);
#pragma unroll
    for (int kk = 0; kk < 2; ++kk) {
      bf16x8 af[4], bff[4];
      const int pc = (kk * 4 + lg) ^ (lq & 7);
#pragma unroll
      for (int f = 0; f < 4; ++f) {
        af[f]  = *reinterpret_cast<const bf16x8*>(&sA[cur][(wm * 64 + f * 16 + lq) * 64 + pc * 8]);
        bff[f] = *reinterpret_cast<const bf16x8*>(&sB[cur][(wn * 64 + f * 16 + lq) * 64 + pc * 8]);
      }
#pragma unroll
      for (int i = 0; i < 4; ++i)
#pragma unroll
        for (int j = 0; j < 4; ++j)
          acc[i][j] = __builtin_amdgcn_mfma_f32_16x16x32_bf16(af[i], bff[j], acc[i][j], 0, 0, 0);
    }
    __syncthreads();
    cur ^= 1;
  }
#undef PSTAGE

#pragma unroll
  for (int j = 0; j < 4; ++j) {
    int c = n0 + wn * 64 + j * 16 + lq;
    float bv = bias[c];
#pragma unroll
    for (int i = 0; i < 4; ++i) {
      int mbase = m0 + wm * 64 + i * 16 + lg * 4;
#pragma unroll
      for (int r = 0; r < 4; ++r) {
        int m = mbase + r;
        oproj[(size_t)m * D_ + c] = acc[i][j][r] + bv;
      }
    }
  }
}

// ---------------- K6: LN + residual (reads padded, writes real) ----------------
__global__ __launch_bounds__(256) void k_ln(const float* __restrict__ op, const float* __restrict__ gamma,
                                            const float* __restrict__ beta, float* __restrict__ out) {
  int row = blockIdx.x;
  int b = row / N_, n = row - b * N_;
  int t = threadIdx.x;
  const float* r = op + ((size_t)b * NP + n) * D_;
  float v0 = r[t], v1 = r[t + 256];
  float s = v0 + v1, sq = v0 * v0 + v1 * v1;
#pragma unroll
  for (int off = 1; off < 64; off <<= 1) { s += __shfl_xor(s, off); sq += __shfl_xor(sq, off); }
  __shared__ float ls[4], lsq[4];
  int wave = t >> 6, lane = t & 63;
  if (lane == 0) { ls[wave] = s; lsq[wave] = sq; }
  __syncthreads();
  float S = ls[0] + ls[1] + ls[2] + ls[3];
  float SQ = lsq[0] + lsq[1] + lsq[2] + lsq[3];
  float mu = S * (1.f / 512.f);
  float var = SQ * (1.f / 512.f) - mu * mu;
  float rinv = rsqrtf(var + 1e-5f);
  float g0 = gamma[t], g1 = gamma[t + 256], b0 = beta[t], b1 = beta[t + 256];
  out[(size_t)row * D_ + t]       = v0 + (v0 - mu) * rinv * g0 + b0;
  out[(size_t)row * D_ + t + 256] = v1 + (v1 - mu) * rinv * g1 + b1;
}

extern "C" void kernel_launch(void* const* d_in, const int* in_sizes, int n_in,
                              void* d_out, int out_size, void* d_ws, size_t ws_size,
                              hipStream_t stream) {
  const float* x     = (const float*)d_in[0];
  const float* wqkv  = (const float*)d_in[1];
  const float* wproj = (const float*)d_in[2];
  const float* bproj = (const float*)d_in[3];
  const float* gamma = (const float*)d_in[4];
  const float* beta  = (const float*)d_in[5];
  const float* mask  = (const float*)d_in[6];
  float* out = (float*)d_out;

  char* ws = (char*)d_ws;
  size_t off = 0;
  auto alloc = [&](size_t bytes) {
    void* p = ws + off;
    off = (off + bytes + 255) & ~(size_t)255;
    return p;
  };
  uint32_t* bmask = (uint32_t*)alloc((size_t)NP * WM * 4);
  u16* wtq  = (u16*)alloc((size_t)3 * D_ * D_ * 2);
  u16* wtp  = (u16*)alloc((size_t)D_ * D_ * 2);
  u16* xb   = (u16*)alloc((size_t)MP * D_ * 2);
  u16* Qb   = (u16*)alloc((size_t)128 * NP * HD * 2);
  u16* Kb   = (u16*)alloc((size_t)128 * NP * HD * 2);
  u16* Vb   = (u16*)alloc((size_t)128 * NP * HD * 2);
  u16* Vtb  = (u16*)alloc((size_t)128 * HD * NP * 2);
  u16* Ob   = (u16*)alloc((size_t)MP * D_ * 2);
  float* oproj = (float*)alloc((size_t)MP * D_ * 4);

  k_bitmask<<<dim3(NP), dim3(256), 0, stream>>>(mask, bmask);
  k_wconv<<<dim3(3072), dim3(256), 0, stream>>>(wqkv, wproj, wtq, wtp);
  k_xconv<<<dim3(MP * D_ / (256 * 8)), dim3(256), 0, stream>>>(x, xb);
  k_qkv<<<dim3(12, MP / 128), dim3(256), 0, stream>>>(xb, wtq, Qb, Kb, Vb);
  k_vt<<<dim3(NP / 64, 128), dim3(256), 0, stream>>>(Vb, Vtb);
  k_attn<<<dim3(NT * 128), dim3(256), 0, stream>>>(Qb, Kb, Vtb, bmask, Ob);
  k_proj<<<dim3(4, MP / 128), dim3(256), 0, stream>>>(Ob, wtp, bproj, oproj);
  k_ln<<<dim3(M_), dim3(256), 0, stream>>>(oproj, gamma, beta, out);
}